// Round 8
// baseline (198.725 us; speedup 1.0000x reference)
//
#include <hip/hip_runtime.h>

// Problem dims (fixed by reference): B=8, L=4096, K=32, C=64, KC=2048
#define B_DIM 8
#define L_DIM 4096
#define KC 2048              // K*C, contiguous innermost span per (b,l)
#define PT   512             // threads: one float4 column each
#define NSEG 128             // segments per b for reduce duty (lrows = 32)
#define LROWS (L_DIM / NSEG)             // 32
#define WBPB 128                         // bcast blocks per b (32 rows each)
#define WROWS (L_DIM / WBPB)             // 32

typedef float f4 __attribute__((ext_vector_type(4)));
typedef int   i4 __attribute__((ext_vector_type(4)));

// ---------------------------------------------------------------------------
// Duty helpers. Thread t owns float4 column t of each 8 KB row.
// ---------------------------------------------------------------------------
__device__ __forceinline__ void reduce_duty(const float* __restrict__ x,
                                            const int* __restrict__ mask,
                                            float* __restrict__ psum,
                                            float* __restrict__ pcnt,
                                            int b, int seg, int t) {
    const long base = ((long)b * L_DIM + (long)seg * LROWS) * KC + t * 4;

    f4 s = {0.f, 0.f, 0.f, 0.f};
    f4 c = {0.f, 0.f, 0.f, 0.f};

    #pragma unroll 4
    for (int l = 0; l < LROWS; ++l) {
        const f4 xv = __builtin_nontemporal_load(
                          (const f4*)(x + base + (long)l * KC));
        const i4 mv = *(const i4*)(mask + base + (long)l * KC);
        float m0 = (float)mv.x, m1 = (float)mv.y, m2 = (float)mv.z, m3 = (float)mv.w;
        s.x = fmaf(xv.x, m0, s.x);  c.x += m0;
        s.y = fmaf(xv.y, m1, s.y);  c.y += m1;
        s.z = fmaf(xv.z, m2, s.z);  c.z += m2;
        s.w = fmaf(xv.w, m3, s.w);  c.w += m3;
    }

    const long po = ((long)b * NSEG + seg) * KC + t * 4;
    *(f4*)(&psum[po]) = s;
    *(f4*)(&pcnt[po]) = c;
}

__device__ __forceinline__ void bcast_duty(const float* __restrict__ mean,
                                           float* __restrict__ out,
                                           int b, int seg, int t) {
    const f4 v = *(const f4*)(&mean[(long)b * KC + t * 4]);
    const long base = ((long)b * L_DIM + (long)seg * WROWS) * KC + t * 4;
    #pragma unroll
    for (int l = 0; l < WROWS; ++l)
        *(f4*)(out + base + (long)l * KC) = v;
}

// ---------------------------------------------------------------------------
// K1: partial reduce for b in [0, 6). 768 blocks.
// ---------------------------------------------------------------------------
__global__ __launch_bounds__(PT) void partialA_k(const float* __restrict__ x,
                                                 const int* __restrict__ mask,
                                                 float* __restrict__ psum,
                                                 float* __restrict__ pcnt) {
    reduce_duty(x, mask, psum, pcnt, blockIdx.x / NSEG, blockIdx.x % NSEG,
                threadIdx.x);
}

// ---------------------------------------------------------------------------
// mean fold for nb batches starting at b0. nb*KC threads.
// ---------------------------------------------------------------------------
__global__ __launch_bounds__(256) void mean_k(const float* __restrict__ psum,
                                              const float* __restrict__ pcnt,
                                              float* __restrict__ mean,
                                              int b0) {
    const int i = blockIdx.x * 256 + threadIdx.x;   // 0 .. nb*KC-1
    const int b = b0 + i / KC;
    const int j = i % KC;

    float s = 0.f, c = 0.f;
    #pragma unroll 4
    for (int seg = 0; seg < NSEG; ++seg) {
        const long o = ((long)b * NSEG + seg) * KC + j;
        s += psum[o];
        c += pcnt[o];
    }
    mean[(long)b * KC + j] = (c > 0.f) ? (s / c) : 0.f;
}

// ---------------------------------------------------------------------------
// K3: mixed duty — blocks 0..255 reduce b in {6,7} (reads),
//     blocks 256..1023 broadcast b in [0,6) (writes). Reads and writes
//     flow on concurrently-usable paths (read cap ~3.6 TB/s, write ~7).
// ---------------------------------------------------------------------------
__global__ __launch_bounds__(PT) void mix_k(const float* __restrict__ x,
                                            const int* __restrict__ mask,
                                            float* __restrict__ psum,
                                            float* __restrict__ pcnt,
                                            const float* __restrict__ mean,
                                            float* __restrict__ out) {
    const int t = threadIdx.x;
    if (blockIdx.x < 2 * NSEG) {
        const int bi = blockIdx.x;
        reduce_duty(x, mask, psum, pcnt, 6 + bi / NSEG, bi % NSEG, t);
    } else {
        const int wb = blockIdx.x - 2 * NSEG;       // 0 .. 767
        bcast_duty(mean, out, wb / WBPB, wb % WBPB, t);
    }
}

// ---------------------------------------------------------------------------
// K5: broadcast b in {6,7}. 256 blocks.
// ---------------------------------------------------------------------------
__global__ __launch_bounds__(PT) void bcastB_k(const float* __restrict__ mean,
                                               float* __restrict__ out) {
    bcast_duty(mean, out, 6 + blockIdx.x / WBPB, blockIdx.x % WBPB,
               threadIdx.x);
}

extern "C" void kernel_launch(void* const* d_in, const int* in_sizes, int n_in,
                              void* d_out, int out_size, void* d_ws, size_t ws_size,
                              hipStream_t stream) {
    const float* x    = (const float*)d_in[0];
    const int*   mask = (const int*)d_in[1];
    float*       out  = (float*)d_out;
    float*       ws   = (float*)d_ws;

    // ws: psum [B*NSEG*KC] + pcnt [B*NSEG*KC] + mean [B*KC]  = ~16.9 MB
    float* psum = ws;
    float* pcnt = ws + (long)B_DIM * NSEG * KC;
    float* mean = ws + 2l * B_DIM * NSEG * KC;

    // K1: reduce b0..5 (reads 402 MB)
    partialA_k<<<6 * NSEG, PT, 0, stream>>>(x, mask, psum, pcnt);

    // K2: finalize mean for b0..5 (tiny)
    mean_k<<<6 * KC / 256, 256, 0, stream>>>(psum, pcnt, mean, 0);

    // K3: reduce b6..7 (reads 134 MB) || broadcast b0..5 (writes 201 MB)
    mix_k<<<2 * NSEG + 6 * WBPB, PT, 0, stream>>>(x, mask, psum, pcnt,
                                                  mean, out);

    // K4: finalize mean for b6..7 (tiny)
    mean_k<<<2 * KC / 256, 256, 0, stream>>>(psum, pcnt, mean, 6);

    // K5: broadcast b6..7 (writes 67 MB)
    bcastB_k<<<2 * WBPB, PT, 0, stream>>>(mean, out);
}

// Round 9
// 188.647 us; speedup vs baseline: 1.0534x; 1.0534x over previous
//
#include <hip/hip_runtime.h>

// Problem dims (fixed by reference): B=8, L=4096, K=32, C=64, KC=2048
#define B_DIM 8
#define L_DIM 4096
#define KC 2048              // K*C, contiguous innermost span per (b,l)
#define LCB  16              // l-rows per bcast block -> 2048 blocks
#define PT   512             // threads: one float4 column each

typedef float f4 __attribute__((ext_vector_type(4)));
typedef int   i4 __attribute__((ext_vector_type(4)));

// ---------------------------------------------------------------------------
// Stage 1: per-(b,segment) private partial sums/counts. No atomics.
// Measured invariants (R3/R5/R7): streaming-read phase caps ~3.6 TB/s
// regardless of MLP depth, occupancy, or L3-residency; duty-mixing with
// writes (R8) regresses. Keep the simple compiler-scheduled form.
// x is a zero-reuse stream: nontemporal loads keep it from evicting the
// L3-resident mask / absorbed out lines (R7: -6 us).
// ---------------------------------------------------------------------------
__global__ __launch_bounds__(PT) void partial_k(const float* __restrict__ x,
                                                const int* __restrict__ mask,
                                                float* __restrict__ psum,
                                                float* __restrict__ pcnt,
                                                int nseg, int lrows) {
    const int b   = blockIdx.x / nseg;
    const int seg = blockIdx.x % nseg;
    const int t   = threadIdx.x;

    const long base = ((long)b * L_DIM + (long)seg * lrows) * KC + t * 4;

    f4 s = {0.f, 0.f, 0.f, 0.f};
    f4 c = {0.f, 0.f, 0.f, 0.f};

    #pragma unroll 4
    for (int l = 0; l < lrows; ++l) {
        const f4 xv = __builtin_nontemporal_load(
                          (const f4*)(x + base + (long)l * KC));
        const i4 mv = *(const i4*)(mask + base + (long)l * KC);
        float m0 = (float)mv.x, m1 = (float)mv.y, m2 = (float)mv.z, m3 = (float)mv.w;
        s.x = fmaf(xv.x, m0, s.x);  c.x += m0;
        s.y = fmaf(xv.y, m1, s.y);  c.y += m1;
        s.z = fmaf(xv.z, m2, s.z);  c.z += m2;
        s.w = fmaf(xv.w, m3, s.w);  c.w += m3;
    }

    const long po = ((long)b * nseg + seg) * KC + t * 4;
    *(f4*)(&psum[po]) = s;
    *(f4*)(&pcnt[po]) = c;
}

// ---------------------------------------------------------------------------
// Stage 2: fold nseg partials per (b,j), finalize mean. B*KC = 16384 threads.
// ---------------------------------------------------------------------------
__global__ __launch_bounds__(256) void mean_k(const float* __restrict__ psum,
                                              const float* __restrict__ pcnt,
                                              float* __restrict__ mean,
                                              int nseg) {
    const int i = blockIdx.x * 256 + threadIdx.x;   // 0 .. B*KC-1
    const int b = i / KC;
    const int j = i % KC;

    float s = 0.f, c = 0.f;
    #pragma unroll 4
    for (int seg = 0; seg < nseg; ++seg) {
        const long o = ((long)b * nseg + seg) * KC + j;
        s += psum[o];
        c += pcnt[o];
    }
    mean[i] = (c > 0.f) ? (s / c) : 0.f;
}

// ---------------------------------------------------------------------------
// Stage 3: broadcast mean[b,:,:] to all L rows. mean is 64 KB -> L2-resident.
// Normal (cacheable) stores: L3 absorption of out re-writes between replays
// is measured profit — do NOT make these nontemporal.
// ---------------------------------------------------------------------------
__global__ __launch_bounds__(PT) void bcast_k(const float* __restrict__ mean,
                                              float* __restrict__ out) {
    const int blocks_per_b = L_DIM / LCB;           // 256
    const int b    = blockIdx.x / blocks_per_b;
    const int lseg = blockIdx.x % blocks_per_b;
    const int t    = threadIdx.x;

    const f4 v = *(const f4*)(&mean[(long)b * KC + t * 4]);

    const long base = ((long)b * L_DIM + (long)lseg * LCB) * KC + t * 4;
    #pragma unroll
    for (int l = 0; l < LCB; ++l)
        *(f4*)(out + base + (long)l * KC) = v;
}

extern "C" void kernel_launch(void* const* d_in, const int* in_sizes, int n_in,
                              void* d_out, int out_size, void* d_ws, size_t ws_size,
                              hipStream_t stream) {
    const float* x    = (const float*)d_in[0];
    const int*   mask = (const int*)d_in[1];
    float*       out  = (float*)d_out;
    float*       ws   = (float*)d_ws;

    // nseg=128 (R3/R7 best): partials = 16.8 MB, lrows = 32.
    int nseg = 128;
    while (nseg > 8 &&
           (size_t)(2ul * B_DIM * nseg * KC + B_DIM * KC) * 4ul > ws_size)
        nseg >>= 1;
    const int lrows = L_DIM / nseg;

    float* psum = ws;
    float* pcnt = ws + (long)B_DIM * nseg * KC;
    float* mean = ws + 2l * B_DIM * nseg * KC;

    // 1) private partial sums/counts (no atomics)
    partial_k<<<B_DIM * nseg, PT, 0, stream>>>(x, mask, psum, pcnt,
                                               nseg, lrows);

    // 2) fold partials, finalize mean
    mean_k<<<(B_DIM * KC) / 256, 256, 0, stream>>>(psum, pcnt, mean, nseg);

    // 3) broadcast to [B, L, K, C]
    bcast_k<<<B_DIM * (L_DIM / LCB), PT, 0, stream>>>(mean, out);
}